// Round 4
// 1403.193 us; speedup vs baseline: 9.5093x; 9.5093x over previous
//
#include <hip/hip_runtime.h>
#include <hip/hip_bf16.h>

// LlamaSdpaAttention: B=2, S=2048, HIDDEN=4096, NH=32, NKV=8, D=128, theta=5e5
// Round 9: identical source to round 8 (round-8 bench died of container infra,
// kernel never ran). Round 6/7 failed identically (absmax 5.4375) because
// acc_o[4] with d = dj*16+m16 only covered head dims 0..63 — half of D=128.
// Fixed: acc_o[8], dj loops 0..7 in rescale/PV/epilogue. Attn is otherwise the
// round-7 swapped-operand flash kernel (P per-lane, register redistribution).
// Poison kernel pre-fills attn output so a silent non-write is unmistakable.
// conv(fp32->bf16) -> gemm(qkv) -> rope -> flash attn (MFMA) -> gemm(out, fp32).

typedef __attribute__((ext_vector_type(8))) short bf16x8;   // 8 bf16 = 4 VGPRs
typedef __attribute__((ext_vector_type(4))) float floatx4;  // MFMA C/D frag
using bf16 = __hip_bfloat16;

#define LOG2E 1.44269504088896340736f

__device__ __forceinline__ void store_out(bf16* p, float v) { *p = __float2bfloat16(v); }
__device__ __forceinline__ void store_out(float* p, float v) { *p = v; }

// pack two floats into one u32 of 2 bf16 (lo = a, hi = b)
__device__ __forceinline__ unsigned pk2(float a, float b)
{
  union { bf16 h; unsigned short s; } A, B;
  A.h = __float2bfloat16(a);
  B.h = __float2bfloat16(b);
  return (unsigned)A.s | ((unsigned)B.s << 16);
}

// ---------------------------------------------------------------------------
// Convert unknown-dtype (fp32 or bf16) array to bf16.
// ---------------------------------------------------------------------------
__global__ __launch_bounds__(256) void conv_to_bf16(const void* __restrict__ src,
                                                    bf16* __restrict__ dst,
                                                    size_t n)
{
  const unsigned* u32 = (const unsigned*)src;
  int score = 0;
#pragma unroll
  for (int i = 0; i < 16; i++) {
    unsigned e = (u32[i] >> 7) & 0xFF;  // low-half bf16 exponent field
    score += (e >= 0x6E && e <= 0x84) ? 1 : 0;
  }
  const bool is_bf16 = score >= 12;
  size_t i = ((size_t)blockIdx.x * 256 + threadIdx.x) * 8;
  if (i >= n) return;
  if (is_bf16) {
    *(bf16x8*)(dst + i) = *(const bf16x8*)((const bf16*)src + i);
  } else {
    const float* f = (const float*)src;
    bf16 tmp[8];
#pragma unroll
    for (int j = 0; j < 8; j++) tmp[j] = __float2bfloat16(f[i + j]);
    *(bf16x8*)(dst + i) = *(bf16x8*)tmp;
  }
}

// ---------------------------------------------------------------------------
// Poison: fill a bf16 buffer with 0x7070 (~4.6e33). If the attention kernel
// ever fails to write its output, the final GEMM explodes -> unmistakable.
// ---------------------------------------------------------------------------
__global__ __launch_bounds__(256) void poison_bf16(bf16* __restrict__ dst)
{
  size_t i = ((size_t)blockIdx.x * 256 + threadIdx.x) * 8;
  const short p = 0x7070;
  bf16x8 v = {p, p, p, p, p, p, p, p};
  *(bf16x8*)(dst + i) = v;
}

// ---------------------------------------------------------------------------
// GEMM: C[M,N] = A[M,K] @ B[N,K]^T, bf16 in, fp32 accumulate, OT out.
// 128x128 tile, BK=64, 256 threads (4 waves, each 64x64), 16x16x32 bf16 MFMA.
// ---------------------------------------------------------------------------
template <typename OT>
__global__ __launch_bounds__(256) void gemm_bt(const bf16* __restrict__ A,
                                               const bf16* __restrict__ B,
                                               OT* __restrict__ C,
                                               int M, int N, int K)
{
  __shared__ bf16 As[128 * 64];
  __shared__ bf16 Bs[128 * 64];
  const int tid  = threadIdx.x;
  const int wave = tid >> 6, lane = tid & 63;
  const int quad = lane >> 4, m16 = lane & 15;
  const int m0 = blockIdx.y * 128, n0 = blockIdx.x * 128;
  const int wr = (wave >> 1) * 64, wc = (wave & 1) * 64;

  floatx4 acc[4][4];
#pragma unroll
  for (int i = 0; i < 4; i++)
#pragma unroll
    for (int j = 0; j < 4; j++) acc[i][j] = (floatx4){0.f, 0.f, 0.f, 0.f};

  const int srow = tid >> 3;        // 0..31  (+32 per step)
  const int scol = (tid & 7) * 8;   // 0..56

  for (int kt = 0; kt < K; kt += 64) {
    bf16x8 sa[4], sb[4];
#pragma unroll
    for (int i = 0; i < 4; i++) {
      sa[i] = *(const bf16x8*)(A + (size_t)(m0 + srow + i * 32) * K + kt + scol);
      sb[i] = *(const bf16x8*)(B + (size_t)(n0 + srow + i * 32) * K + kt + scol);
    }
#pragma unroll
    for (int i = 0; i < 4; i++) {
      *(bf16x8*)(As + (srow + i * 32) * 64 + scol) = sa[i];
      *(bf16x8*)(Bs + (srow + i * 32) * 64 + scol) = sb[i];
    }
    __syncthreads();
#pragma unroll
    for (int kk = 0; kk < 2; ++kk) {
      bf16x8 a[4], b[4];
#pragma unroll
      for (int i = 0; i < 4; i++)
        a[i] = *(const bf16x8*)(As + (wr + i * 16 + m16) * 64 + kk * 32 + quad * 8);
#pragma unroll
      for (int j = 0; j < 4; j++)
        b[j] = *(const bf16x8*)(Bs + (wc + j * 16 + m16) * 64 + kk * 32 + quad * 8);
#pragma unroll
      for (int i = 0; i < 4; i++)
#pragma unroll
        for (int j = 0; j < 4; j++)
          acc[i][j] = __builtin_amdgcn_mfma_f32_16x16x32_bf16(a[i], b[j], acc[i][j], 0, 0, 0);
    }
    __syncthreads();
  }

  // C/D layout: col = lane&15, row = quad*4 + reg  [verified m89/m91]
  const int row = m0 + wr + quad * 4;
  const int col = n0 + wc + m16;
#pragma unroll
  for (int i = 0; i < 4; i++)
#pragma unroll
    for (int j = 0; j < 4; j++)
#pragma unroll
      for (int r = 0; r < 4; r++)
        store_out(&C[(size_t)(row + i * 16 + r) * N + col + j * 16], acc[i][j][r]);
}

// ---------------------------------------------------------------------------
// RoPE in place on q [4096 x 4096] and k [4096 x 1024].
// ---------------------------------------------------------------------------
__global__ __launch_bounds__(256) void rope_kernel(bf16* __restrict__ q,
                                                   bf16* __restrict__ k,
                                                   const int* __restrict__ pos)
{
  int idx = blockIdx.x * 256 + threadIdx.x;  // 4096 * 2048 threads
  int row = idx >> 11;
  int p   = idx & 2047;
  int h   = p >> 6, j = p & 63;
  const bool p64 = (pos[1] == 0);
  float t = (float)(p64 ? pos[2 * row] : pos[row]);
  // inv_freq = theta^(-j/64) ; log2(500000) = 18.9315685693
  float inv_freq = exp2f(-(float)j * (18.9315685693241741f / 64.0f));
  float fr = t * inv_freq;
  float s, c;
  sincosf(fr, &s, &c);

  size_t base = (size_t)row * 4096 + h * 128 + j;
  float a  = __bfloat162float(q[base]);
  float b2 = __bfloat162float(q[base + 64]);
  q[base]      = __float2bfloat16(a * c - b2 * s);
  q[base + 64] = __float2bfloat16(b2 * c + a * s);
  if (h < 8) {
    size_t kb = (size_t)row * 1024 + h * 128 + j;
    a  = __bfloat162float(k[kb]);
    b2 = __bfloat162float(k[kb + 64]);
    k[kb]      = __float2bfloat16(a * c - b2 * s);
    k[kb + 64] = __float2bfloat16(b2 * c + a * s);
  }
}

// ---------------------------------------------------------------------------
// Flash-style MFMA attention, swapped-operand form. (Round-7 kernel with the
// half-head-dim bug fixed: acc_o[8], dj = 0..7.)
//
// Grid: (S/64, H, B). Block: 256 threads = 4 waves; wave w owns q rows
// [q0+16w, q0+16w+16). Loop over 64-key tiles; causal via loop bound,
// diagonal tile masked in-register.
//
// QK^T is computed SWAPPED: sacc[j] = mfma(K_frag, Q_frag) so that
//   sacc[j][r] (lane quad,m16) = S[q = m16][key = j*16 + quad*4 + r].
// => softmax state (m, l) is per-lane scalar for q-row m16 (quads redundant;
//    key-reduce = in-lane + shfl_xor 16, 32).
// P redistribution to the PV A-operand (A[row=q=m16][k=key]) is register
// shuffles only: lane (quad,m16) needs keys kk*32+quad*8+{0..7}, which live
// as j = 2kk+(quad>>1), offsets (quad&1)*8.. at source quads (quad&1)*2 and
// (quad&1)*2+1. Verified: key = kk*32 + (quad>>1)*16 + (quad&1)*8 + r ==
// kk*32 + quad*8 + r for all quad. 16 shfl + 8 selects per tile. No LDS P.
//
// LDS:
//   Ks[64][136]     K tile row-major, +8 pad (272B stride = 4 banks mod 32)
//   Vs[8][128][8]   V tile as [n>>3][d][n&7]: PV B-frag = one ds_read_b128,
//                   vf[jj] = V[key=(kk*4+quad)*8+jj][d=dj*16+m16]
// ---------------------------------------------------------------------------
__global__ __launch_bounds__(256) void attn_mfma(const bf16* __restrict__ q,
                                                 const bf16* __restrict__ k,
                                                 const bf16* __restrict__ v,
                                                 bf16* __restrict__ o)
{
  constexpr int KP = 136;
  __shared__ alignas(16) bf16 Ks[64 * KP];      // 17408 B
  __shared__ alignas(16) bf16 Vs[8 * 128 * 8];  // 16384 B (33792 B total)

  const int tid = threadIdx.x, w = tid >> 6, lane = tid & 63;
  const int quad = lane >> 4, m16 = lane & 15;
  const int q0 = blockIdx.x * 64, h = blockIdx.y, b = blockIdx.z, g = h >> 2;

  // Q fragments (B-operand for swapped QK^T): lane holds
  // Q[q0 + w*16 + m16][h*128 + kk*32 + quad*8 + jj]
  bf16x8 qf[4];
  {
    const bf16* qp = q + (size_t)(b * 2048 + q0 + w * 16 + m16) * 4096 + h * 128 + quad * 8;
#pragma unroll
    for (int kk = 0; kk < 4; kk++) qf[kk] = *(const bf16x8*)(qp + kk * 32);
  }

  floatx4 acc_o[8];  // FULL D=128: dj = 0..7 covers d = dj*16 + m16 in 0..127
#pragma unroll
  for (int dj = 0; dj < 8; dj++) acc_o[dj] = (floatx4){0.f, 0.f, 0.f, 0.f};
  float m_run = -1e30f;  // running max (log2 domain), q-row = m16
  float l_run = 0.f;     // running denom,             q-row = m16

  const int srow = tid >> 4;        // 0..15
  const int scol = (tid & 15) * 8;  // 0..120
  const int rot  = tid & 15;
  const float sl2 = 0.08838834764831843f * LOG2E;  // scale folded into log2 dom
  const int nt = blockIdx.x + 1;

  for (int t = 0; t < nt; ++t) {
    const size_t kvbase = (size_t)(b * 2048 + t * 64) * 1024 + g * 128;

    // ---- stage K tile (row-major) and V tile ([n>>3][d][n&7]) ----
#pragma unroll
    for (int p = 0; p < 4; p++) {
      const int r = srow + p * 16;  // key row 0..63
      *(bf16x8*)(Ks + r * KP + scol) =
          *(const bf16x8*)(k + kvbase + (size_t)r * 1024 + scol);
      bf16x8 vv = *(const bf16x8*)(v + kvbase + (size_t)r * 1024 + scol);
      union { bf16x8 v8; unsigned u[4]; } U;
      U.v8 = vv;
      const unsigned long long lo = U.u[0] | ((unsigned long long)U.u[1] << 32);
      const unsigned long long hi = U.u[2] | ((unsigned long long)U.u[3] << 32);
      const int nhi = r >> 3, nlo = r & 7;
      // transposing scatter; lane-rotated order reduces write bank conflicts;
      // 64-bit shift extraction avoids runtime-indexed arrays (no scratch).
#pragma unroll
      for (int s2 = 0; s2 < 8; s2++) {
        const int jj = (s2 + rot) & 7;
        const unsigned long long src = (jj & 4) ? hi : lo;
        const unsigned short val = (unsigned short)(src >> ((jj & 3) << 4));
        *(unsigned short*)(Vs + ((nhi * 128 + scol + jj) << 3) + nlo) = val;
      }
    }
    __syncthreads();

    // ---- S^T = K Q^T per wave: sacc[j][r] = S[m16][j*16+quad*4+r] ----
    floatx4 sacc[4];
#pragma unroll
    for (int j = 0; j < 4; j++) sacc[j] = (floatx4){0.f, 0.f, 0.f, 0.f};
#pragma unroll
    for (int kk = 0; kk < 4; kk++) {
#pragma unroll
      for (int j = 0; j < 4; j++) {
        bf16x8 kf = *(const bf16x8*)(Ks + (j * 16 + m16) * KP + kk * 32 + quad * 8);
        sacc[j] = __builtin_amdgcn_mfma_f32_16x16x32_bf16(kf, qf[kk], sacc[j], 0, 0, 0);
      }
    }

    // ---- per-lane online softmax for q-row m16 (log2 domain) ----
    const bool diag = (t == nt - 1);
    float smax = -1e30f;
#pragma unroll
    for (int j = 0; j < 4; j++)
#pragma unroll
      for (int r = 0; r < 4; r++) {
        float s = sacc[j][r] * sl2;
        s = (diag && (j * 16 + quad * 4 + r > w * 16 + m16)) ? -1e30f : s;
        sacc[j][r] = s;
        smax = fmaxf(smax, s);
      }
    smax = fmaxf(smax, __shfl_xor(smax, 16));
    smax = fmaxf(smax, __shfl_xor(smax, 32));
    const float mnew = fmaxf(m_run, smax);
    const float fac = exp2f(m_run - mnew);
    float ps = 0.f;
#pragma unroll
    for (int j = 0; j < 4; j++)
#pragma unroll
      for (int r = 0; r < 4; r++) {
        float p = exp2f(sacc[j][r] - mnew);
        sacc[j][r] = p;
        ps += p;
      }
    ps += __shfl_xor(ps, 16);
    ps += __shfl_xor(ps, 32);
    l_run = l_run * fac + ps;
    m_run = mnew;

    // ---- pack P (bf16 pairs): pl[j] = keys (quad*4+0,+1), ph[j] = (+2,+3) ----
    unsigned pl[4], ph[4];
#pragma unroll
    for (int j = 0; j < 4; j++) {
      pl[j] = pk2(sacc[j][0], sacc[j][1]);
      ph[j] = pk2(sacc[j][2], sacc[j][3]);
    }

    // ---- rescale acc_o (row = quad*4+r; its fac lives at m16 = quad*4+r) ----
    float facr[4];
#pragma unroll
    for (int r = 0; r < 4; r++) facr[r] = __shfl(fac, quad * 20 + r);
#pragma unroll
    for (int dj = 0; dj < 8; dj++)
#pragma unroll
      for (int r = 0; r < 4; r++) acc_o[dj][r] *= facr[r];

    // ---- O += P V  (full D=128: dj = 0..7) ----
    const int sa = (quad & 1) * 32 + m16;  // src quad (quad&1)*2
    const int sb = sa + 16;                // src quad (quad&1)*2 + 1
    const bool hi2 = (quad & 2) != 0;      // j = 2kk + (quad>>1)
#pragma unroll
    for (int kk = 0; kk < 2; kk++) {
      union { bf16x8 v8; int u[4]; } PF;
      int a0 = __shfl((int)pl[2 * kk], sa), a1 = __shfl((int)pl[2 * kk + 1], sa);
      int b0 = __shfl((int)ph[2 * kk], sa), b1 = __shfl((int)ph[2 * kk + 1], sa);
      int c0 = __shfl((int)pl[2 * kk], sb), c1 = __shfl((int)pl[2 * kk + 1], sb);
      int d0 = __shfl((int)ph[2 * kk], sb), d1 = __shfl((int)ph[2 * kk + 1], sb);
      PF.u[0] = hi2 ? a1 : a0;  // keys kk*32+quad*8+{0,1}
      PF.u[1] = hi2 ? b1 : b0;  //                  +{2,3}
      PF.u[2] = hi2 ? c1 : c0;  //                  +{4,5}
      PF.u[3] = hi2 ? d1 : d0;  //                  +{6,7}
#pragma unroll
      for (int dj = 0; dj < 8; dj++) {
        bf16x8 vf = *(const bf16x8*)(Vs + (((kk * 4 + quad) * 128 + dj * 16 + m16) << 3));
        acc_o[dj] = __builtin_amdgcn_mfma_f32_16x16x32_bf16(PF.v8, vf, acc_o[dj], 0, 0, 0);
      }
    }
    __syncthreads();  // protect Ks/Vs before next tile's staging
  }

  // ---- epilogue: O / l  (row = quad*4+r; its l lives at m16 = quad*4+r) ----
  float linv[4];
#pragma unroll
  for (int r = 0; r < 4; r++) linv[r] = 1.0f / __shfl(l_run, quad * 20 + r);
  const int orow = q0 + w * 16 + quad * 4;
#pragma unroll
  for (int r = 0; r < 4; r++)
#pragma unroll
    for (int dj = 0; dj < 8; dj++)
      o[(size_t)(b * 2048 + orow + r) * 4096 + h * 128 + dj * 16 + m16] =
          __float2bfloat16(acc_o[dj][r] * linv[r]);
}

// ---------------------------------------------------------------------------
extern "C" void kernel_launch(void* const* d_in, const int* in_sizes, int n_in,
                              void* d_out, int out_size, void* d_ws, size_t ws_size,
                              hipStream_t stream)
{
  const int* pos = (const int*)d_in[1];
  float* out = (float*)d_out;  // reference output dtype: fp32

  // Workspace layout (112 MB total):
  char* w = (char*)d_ws;
  bf16* xb = (bf16*)w;               // x  converted  [4096][4096]  32 MB
  bf16* ab = xb;                     // attn output aliases xb (x dead by then)
  bf16* wb = (bf16*)(w + (size_t)32 * 1024 * 1024);  // weight staging 32 MB
  bf16* qb = (bf16*)(w + (size_t)64 * 1024 * 1024);  // q [4096][4096] 32 MB
  bf16* kb = (bf16*)(w + (size_t)96 * 1024 * 1024);  // k [4096][1024]  8 MB
  bf16* vb = (bf16*)(w + (size_t)104 * 1024 * 1024); // v [4096][1024]  8 MB

  const size_t NBIG = (size_t)4096 * 4096;   // 16.7M elts
  const size_t NSML = (size_t)4096 * 1024;   // 4.2M elts
  const int GBIG = (int)(NBIG / 8 / 256);    // 8192 blocks
  const int GSML = (int)(NSML / 8 / 256);    // 2048 blocks

  conv_to_bf16<<<GBIG, 256, 0, stream>>>(d_in[0], xb, NBIG);  // x

  conv_to_bf16<<<GBIG, 256, 0, stream>>>(d_in[2], wb, NBIG);  // wq
  gemm_bt<bf16><<<dim3(32, 32), 256, 0, stream>>>(xb, wb, qb, 4096, 4096, 4096);

  conv_to_bf16<<<GSML, 256, 0, stream>>>(d_in[3], wb, NSML);  // wk
  gemm_bt<bf16><<<dim3(8, 32), 256, 0, stream>>>(xb, wb, kb, 4096, 1024, 4096);

  conv_to_bf16<<<GSML, 256, 0, stream>>>(d_in[4], wb, NSML);  // wv
  gemm_bt<bf16><<<dim3(8, 32), 256, 0, stream>>>(xb, wb, vb, 4096, 1024, 4096);

  rope_kernel<<<32768, 256, 0, stream>>>(qb, kb, pos);

  poison_bf16<<<GBIG, 256, 0, stream>>>(ab);  // x dead now; make non-write loud

  attn_mfma<<<dim3(32, 32, 2), 256, 0, stream>>>(qb, kb, vb, ab);

  conv_to_bf16<<<GBIG, 256, 0, stream>>>(d_in[5], wb, NBIG);  // wo
  gemm_bt<float><<<dim3(32, 32), 256, 0, stream>>>(ab, wb, out, 4096, 4096, 4096);
}

// Round 5
// 1279.247 us; speedup vs baseline: 10.4307x; 1.0969x over previous
//
#include <hip/hip_runtime.h>
#include <hip/hip_bf16.h>

// LlamaSdpaAttention: B=2, S=2048, HIDDEN=4096, NH=32, NKV=8, D=128, theta=5e5
// Round 10 (from passing round-9, 1403 us):
//  (1) V projection computed TRANSPOSED (V^T = Wv @ X^T via operand-swapped
//      gemm_bt) -> attn stages V^T tiles linearly, PV B-frags are contiguous
//      ds_read_b128 at pad-72 stride. Removes the 32-op/lane/tile V-scatter
//      that dominated SQ_LDS_BANK_CONFLICT (2.16e7).
//  (2) GEMM staging via __builtin_amdgcn_global_load_lds width=16 (m97
//      recipe): removes VGPR round-trip + ds_writes in all 4 GEMMs.
// conv(fp32->bf16) -> gemm(qkv) -> rope -> flash attn (MFMA) -> gemm(out, fp32).

typedef __attribute__((ext_vector_type(8))) short bf16x8;   // 8 bf16 = 4 VGPRs
typedef __attribute__((ext_vector_type(4))) float floatx4;  // MFMA C/D frag
using bf16 = __hip_bfloat16;

#define LOG2E 1.44269504088896340736f

__device__ __forceinline__ void store_out(bf16* p, float v) { *p = __float2bfloat16(v); }
__device__ __forceinline__ void store_out(float* p, float v) { *p = v; }

// async global->LDS, 16B per lane. LDS dest must be wave-uniform base;
// HW writes base + lane*16. [m03/m97]
__device__ __forceinline__ void gload_lds16(const bf16* g, bf16* l)
{
  __builtin_amdgcn_global_load_lds(
      (const __attribute__((address_space(1))) void*)g,
      (__attribute__((address_space(3))) void*)l, 16, 0, 0);
}

// pack two floats into one u32 of 2 bf16 (lo = a, hi = b)
__device__ __forceinline__ unsigned pk2(float a, float b)
{
  union { bf16 h; unsigned short s; } A, B;
  A.h = __float2bfloat16(a);
  B.h = __float2bfloat16(b);
  return (unsigned)A.s | ((unsigned)B.s << 16);
}

// ---------------------------------------------------------------------------
// Convert unknown-dtype (fp32 or bf16) array to bf16.
// ---------------------------------------------------------------------------
__global__ __launch_bounds__(256) void conv_to_bf16(const void* __restrict__ src,
                                                    bf16* __restrict__ dst,
                                                    size_t n)
{
  const unsigned* u32 = (const unsigned*)src;
  int score = 0;
#pragma unroll
  for (int i = 0; i < 16; i++) {
    unsigned e = (u32[i] >> 7) & 0xFF;  // low-half bf16 exponent field
    score += (e >= 0x6E && e <= 0x84) ? 1 : 0;
  }
  const bool is_bf16 = score >= 12;
  size_t i = ((size_t)blockIdx.x * 256 + threadIdx.x) * 8;
  if (i >= n) return;
  if (is_bf16) {
    *(bf16x8*)(dst + i) = *(const bf16x8*)((const bf16*)src + i);
  } else {
    const float* f = (const float*)src;
    bf16 tmp[8];
#pragma unroll
    for (int j = 0; j < 8; j++) tmp[j] = __float2bfloat16(f[i + j]);
    *(bf16x8*)(dst + i) = *(bf16x8*)tmp;
  }
}

// ---------------------------------------------------------------------------
// Poison: fill a bf16 buffer with 0x7070 (~4.6e33). If the attention kernel
// ever fails to write its output, the final GEMM explodes -> unmistakable.
// ---------------------------------------------------------------------------
__global__ __launch_bounds__(256) void poison_bf16(bf16* __restrict__ dst)
{
  size_t i = ((size_t)blockIdx.x * 256 + threadIdx.x) * 8;
  const short p = 0x7070;
  bf16x8 v = {p, p, p, p, p, p, p, p};
  *(bf16x8*)(dst + i) = v;
}

// ---------------------------------------------------------------------------
// GEMM: C[M,N] = A[M,K] @ B[N,K]^T, bf16 in, fp32 accumulate, OT out.
// 128x128 tile, BK=64, 256 threads (4 waves, each 64x64), 16x16x32 bf16 MFMA.
// Staging: global_load_lds dwordx4 (m97): 16 chunks of 1KB per 16KB buffer,
// wave w stages chunks {c*4+w}; lane l covers row chunk*8 + l/8, col (l&7)*8.
// ---------------------------------------------------------------------------
template <typename OT>
__global__ __launch_bounds__(256) void gemm_bt(const bf16* __restrict__ A,
                                               const bf16* __restrict__ B,
                                               OT* __restrict__ C,
                                               int M, int N, int K)
{
  __shared__ alignas(16) bf16 As[128 * 64];
  __shared__ alignas(16) bf16 Bs[128 * 64];
  const int tid  = threadIdx.x;
  const int wave = tid >> 6, lane = tid & 63;
  const int quad = lane >> 4, m16 = lane & 15;
  const int m0 = blockIdx.y * 128, n0 = blockIdx.x * 128;
  const int wr = (wave >> 1) * 64, wc = (wave & 1) * 64;

  floatx4 acc[4][4];
#pragma unroll
  for (int i = 0; i < 4; i++)
#pragma unroll
    for (int j = 0; j < 4; j++) acc[i][j] = (floatx4){0.f, 0.f, 0.f, 0.f};

  const int lrow = lane >> 3;       // 0..7  (row within 8-row chunk)
  const int lcol = (lane & 7) * 8;  // 0..56

  for (int kt = 0; kt < K; kt += 64) {
#pragma unroll
    for (int c = 0; c < 4; c++) {
      const int chunk = c * 4 + wave;           // 0..15 (uniform per wave)
      const int row = chunk * 8 + lrow;         // 0..127
      gload_lds16(A + (size_t)(m0 + row) * K + kt + lcol, As + chunk * 512);
      gload_lds16(B + (size_t)(n0 + row) * K + kt + lcol, Bs + chunk * 512);
    }
    __syncthreads();  // compiler drains vmcnt before s_barrier
#pragma unroll
    for (int kk = 0; kk < 2; ++kk) {
      bf16x8 a[4], b[4];
#pragma unroll
      for (int i = 0; i < 4; i++)
        a[i] = *(const bf16x8*)(As + (wr + i * 16 + m16) * 64 + kk * 32 + quad * 8);
#pragma unroll
      for (int j = 0; j < 4; j++)
        b[j] = *(const bf16x8*)(Bs + (wc + j * 16 + m16) * 64 + kk * 32 + quad * 8);
#pragma unroll
      for (int i = 0; i < 4; i++)
#pragma unroll
        for (int j = 0; j < 4; j++)
          acc[i][j] = __builtin_amdgcn_mfma_f32_16x16x32_bf16(a[i], b[j], acc[i][j], 0, 0, 0);
    }
    __syncthreads();
  }

  // C/D layout: col = lane&15, row = quad*4 + reg  [verified m89/m91]
  const int row = m0 + wr + quad * 4;
  const int col = n0 + wc + m16;
#pragma unroll
  for (int i = 0; i < 4; i++)
#pragma unroll
    for (int j = 0; j < 4; j++)
#pragma unroll
      for (int r = 0; r < 4; r++)
        store_out(&C[(size_t)(row + i * 16 + r) * N + col + j * 16], acc[i][j][r]);
}

// ---------------------------------------------------------------------------
// RoPE in place on q [4096 x 4096] and k [4096 x 1024].
// ---------------------------------------------------------------------------
__global__ __launch_bounds__(256) void rope_kernel(bf16* __restrict__ q,
                                                   bf16* __restrict__ k,
                                                   const int* __restrict__ pos)
{
  int idx = blockIdx.x * 256 + threadIdx.x;  // 4096 * 2048 threads
  int row = idx >> 11;
  int p   = idx & 2047;
  int h   = p >> 6, j = p & 63;
  const bool p64 = (pos[1] == 0);
  float t = (float)(p64 ? pos[2 * row] : pos[row]);
  // inv_freq = theta^(-j/64) ; log2(500000) = 18.9315685693
  float inv_freq = exp2f(-(float)j * (18.9315685693241741f / 64.0f));
  float fr = t * inv_freq;
  float s, c;
  sincosf(fr, &s, &c);

  size_t base = (size_t)row * 4096 + h * 128 + j;
  float a  = __bfloat162float(q[base]);
  float b2 = __bfloat162float(q[base + 64]);
  q[base]      = __float2bfloat16(a * c - b2 * s);
  q[base + 64] = __float2bfloat16(b2 * c + a * s);
  if (h < 8) {
    size_t kb = (size_t)row * 1024 + h * 128 + j;
    a  = __bfloat162float(k[kb]);
    b2 = __bfloat162float(k[kb + 64]);
    k[kb]      = __float2bfloat16(a * c - b2 * s);
    k[kb + 64] = __float2bfloat16(b2 * c + a * s);
  }
}

// ---------------------------------------------------------------------------
// Flash-style MFMA attention, swapped-operand form, V^T input.
// Grid: (S/64, H, B). Block: 256 threads = 4 waves; wave w owns q rows
// [q0+16w, q0+16w+16). Loop over 64-key tiles; causal via loop bound,
// diagonal tile masked in-register.
//
// QK^T is computed SWAPPED: sacc[j] = mfma(K_frag, Q_frag) so that
//   sacc[j][r] (lane quad,m16) = S[q = m16][key = j*16 + quad*4 + r].
// Softmax state is per-lane scalar for q-row m16 (quads redundant; key-reduce
// = in-lane + shfl_xor 16, 32). P redistribution to the PV A-operand is
// register shuffles only (verified round 9). No LDS P.
//
// LDS:
//   Ks[64][136]   K tile row-major, +8 pad (68-word stride -> b128 frag reads
//                 at 8 lanes/4-bank-cluster = conflict-free-equivalent)
//   Vt[128][72]   V^T tile: Vt[d][key]. Staged linearly from vt global
//                 (coalesced along s). PV B-frag = one contiguous
//                 ds_read_b128; 36-word stride -> same 8-cycle ideal.
// ---------------------------------------------------------------------------
__global__ __launch_bounds__(256) void attn_mfma(const bf16* __restrict__ q,
                                                 const bf16* __restrict__ k,
                                                 const bf16* __restrict__ vt,
                                                 bf16* __restrict__ o)
{
  constexpr int KP = 136;
  constexpr int VP = 72;
  __shared__ alignas(16) bf16 Ks[64 * KP];   // 17408 B
  __shared__ alignas(16) bf16 Vt[128 * VP];  // 18432 B (35840 B total)

  const int tid = threadIdx.x, w = tid >> 6, lane = tid & 63;
  const int quad = lane >> 4, m16 = lane & 15;
  const int q0 = blockIdx.x * 64, h = blockIdx.y, b = blockIdx.z, g = h >> 2;

  // Q fragments (B-operand for swapped QK^T): lane holds
  // Q[q0 + w*16 + m16][h*128 + kk*32 + quad*8 + jj]
  bf16x8 qf[4];
  {
    const bf16* qp = q + (size_t)(b * 2048 + q0 + w * 16 + m16) * 4096 + h * 128 + quad * 8;
#pragma unroll
    for (int kk = 0; kk < 4; kk++) qf[kk] = *(const bf16x8*)(qp + kk * 32);
  }

  floatx4 acc_o[8];  // full D=128: dj = 0..7 covers d = dj*16 + m16
#pragma unroll
  for (int dj = 0; dj < 8; dj++) acc_o[dj] = (floatx4){0.f, 0.f, 0.f, 0.f};
  float m_run = -1e30f;  // running max (log2 domain), q-row = m16
  float l_run = 0.f;     // running denom,             q-row = m16

  const int srow = tid >> 4;        // 0..15   (K staging)
  const int scol = (tid & 15) * 8;  // 0..120
  const int vrow8 = tid >> 3;       // 0..31   (Vt staging)
  const int vcol = (tid & 7) * 8;   // 0..56
  const float sl2 = 0.08838834764831843f * LOG2E;  // scale folded into log2 dom
  const int nt = blockIdx.x + 1;

  for (int t = 0; t < nt; ++t) {
    const size_t kvbase = (size_t)(b * 2048 + t * 64) * 1024 + g * 128;
    const bf16* vsrc = vt + (size_t)(g * 128) * 4096 + (size_t)b * 2048 + t * 64;

    // ---- stage K tile (row-major, padded) and V^T tile (linear) ----
#pragma unroll
    for (int p = 0; p < 4; p++) {
      const int r = srow + p * 16;  // key row 0..63
      *(bf16x8*)(Ks + r * KP + scol) =
          *(const bf16x8*)(k + kvbase + (size_t)r * 1024 + scol);
      const int vr = vrow8 + p * 32;  // d row 0..127
      *(bf16x8*)(Vt + vr * VP + vcol) =
          *(const bf16x8*)(vsrc + (size_t)vr * 4096 + vcol);
    }
    __syncthreads();

    // ---- S^T = K Q^T per wave: sacc[j][r] = S[m16][j*16+quad*4+r] ----
    floatx4 sacc[4];
#pragma unroll
    for (int j = 0; j < 4; j++) sacc[j] = (floatx4){0.f, 0.f, 0.f, 0.f};
#pragma unroll
    for (int kk = 0; kk < 4; kk++) {
#pragma unroll
      for (int j = 0; j < 4; j++) {
        bf16x8 kf = *(const bf16x8*)(Ks + (j * 16 + m16) * KP + kk * 32 + quad * 8);
        sacc[j] = __builtin_amdgcn_mfma_f32_16x16x32_bf16(kf, qf[kk], sacc[j], 0, 0, 0);
      }
    }

    // ---- per-lane online softmax for q-row m16 (log2 domain) ----
    const bool diag = (t == nt - 1);
    float smax = -1e30f;
#pragma unroll
    for (int j = 0; j < 4; j++)
#pragma unroll
      for (int r = 0; r < 4; r++) {
        float s = sacc[j][r] * sl2;
        s = (diag && (j * 16 + quad * 4 + r > w * 16 + m16)) ? -1e30f : s;
        sacc[j][r] = s;
        smax = fmaxf(smax, s);
      }
    smax = fmaxf(smax, __shfl_xor(smax, 16));
    smax = fmaxf(smax, __shfl_xor(smax, 32));
    const float mnew = fmaxf(m_run, smax);
    const float fac = exp2f(m_run - mnew);
    float ps = 0.f;
#pragma unroll
    for (int j = 0; j < 4; j++)
#pragma unroll
      for (int r = 0; r < 4; r++) {
        float p = exp2f(sacc[j][r] - mnew);
        sacc[j][r] = p;
        ps += p;
      }
    ps += __shfl_xor(ps, 16);
    ps += __shfl_xor(ps, 32);
    l_run = l_run * fac + ps;
    m_run = mnew;

    // ---- pack P (bf16 pairs): pl[j] = keys (quad*4+0,+1), ph[j] = (+2,+3) ----
    unsigned pl[4], ph[4];
#pragma unroll
    for (int j = 0; j < 4; j++) {
      pl[j] = pk2(sacc[j][0], sacc[j][1]);
      ph[j] = pk2(sacc[j][2], sacc[j][3]);
    }

    // ---- rescale acc_o (row = quad*4+r; its fac lives at m16 = quad*4+r) ----
    float facr[4];
#pragma unroll
    for (int r = 0; r < 4; r++) facr[r] = __shfl(fac, quad * 20 + r);
#pragma unroll
    for (int dj = 0; dj < 8; dj++)
#pragma unroll
      for (int r = 0; r < 4; r++) acc_o[dj][r] *= facr[r];

    // ---- O += P V  (full D=128: dj = 0..7) ----
    const int sa = (quad & 1) * 32 + m16;  // src quad (quad&1)*2
    const int sb = sa + 16;                // src quad (quad&1)*2 + 1
    const bool hi2 = (quad & 2) != 0;      // j = 2kk + (quad>>1)
#pragma unroll
    for (int kk = 0; kk < 2; kk++) {
      union { bf16x8 v8; int u[4]; } PF;
      int a0 = __shfl((int)pl[2 * kk], sa), a1 = __shfl((int)pl[2 * kk + 1], sa);
      int b0 = __shfl((int)ph[2 * kk], sa), b1 = __shfl((int)ph[2 * kk + 1], sa);
      int c0 = __shfl((int)pl[2 * kk], sb), c1 = __shfl((int)pl[2 * kk + 1], sb);
      int d0 = __shfl((int)ph[2 * kk], sb), d1 = __shfl((int)ph[2 * kk + 1], sb);
      PF.u[0] = hi2 ? a1 : a0;  // keys kk*32+quad*8+{0,1}
      PF.u[1] = hi2 ? b1 : b0;  //                  +{2,3}
      PF.u[2] = hi2 ? c1 : c0;  //                  +{4,5}
      PF.u[3] = hi2 ? d1 : d0;  //                  +{6,7}
#pragma unroll
      for (int dj = 0; dj < 8; dj++) {
        bf16x8 vf = *(const bf16x8*)(Vt + (dj * 16 + m16) * VP + kk * 32 + quad * 8);
        acc_o[dj] = __builtin_amdgcn_mfma_f32_16x16x32_bf16(PF.v8, vf, acc_o[dj], 0, 0, 0);
      }
    }
    __syncthreads();  // protect Ks/Vt before next tile's staging
  }

  // ---- epilogue: O / l  (row = quad*4+r; its l lives at m16 = quad*4+r) ----
  float linv[4];
#pragma unroll
  for (int r = 0; r < 4; r++) linv[r] = 1.0f / __shfl(l_run, quad * 20 + r);
  const int orow = q0 + w * 16 + quad * 4;
#pragma unroll
  for (int r = 0; r < 4; r++)
#pragma unroll
    for (int dj = 0; dj < 8; dj++)
      o[(size_t)(b * 2048 + orow + r) * 4096 + h * 128 + dj * 16 + m16] =
          __float2bfloat16(acc_o[dj][r] * linv[r]);
}

// ---------------------------------------------------------------------------
extern "C" void kernel_launch(void* const* d_in, const int* in_sizes, int n_in,
                              void* d_out, int out_size, void* d_ws, size_t ws_size,
                              hipStream_t stream)
{
  const int* pos = (const int*)d_in[1];
  float* out = (float*)d_out;  // reference output dtype: fp32

  // Workspace layout (112 MB total):
  char* w = (char*)d_ws;
  bf16* xb = (bf16*)w;               // x  converted  [4096][4096]  32 MB
  bf16* ab = xb;                     // attn output aliases xb (x dead by then)
  bf16* wb = (bf16*)(w + (size_t)32 * 1024 * 1024);  // weight staging 32 MB
  bf16* qb = (bf16*)(w + (size_t)64 * 1024 * 1024);  // q  [4096][4096] 32 MB
  bf16* kb = (bf16*)(w + (size_t)96 * 1024 * 1024);  // k  [4096][1024]  8 MB
  bf16* vtb = (bf16*)(w + (size_t)104 * 1024 * 1024);// v^T [1024][4096]  8 MB

  const size_t NBIG = (size_t)4096 * 4096;   // 16.7M elts
  const size_t NSML = (size_t)4096 * 1024;   // 4.2M elts
  const int GBIG = (int)(NBIG / 8 / 256);    // 8192 blocks
  const int GSML = (int)(NSML / 8 / 256);    // 2048 blocks

  conv_to_bf16<<<GBIG, 256, 0, stream>>>(d_in[0], xb, NBIG);  // x

  conv_to_bf16<<<GBIG, 256, 0, stream>>>(d_in[2], wb, NBIG);  // wq
  gemm_bt<bf16><<<dim3(32, 32), 256, 0, stream>>>(xb, wb, qb, 4096, 4096, 4096);

  conv_to_bf16<<<GSML, 256, 0, stream>>>(d_in[3], wb, NSML);  // wk
  gemm_bt<bf16><<<dim3(8, 32), 256, 0, stream>>>(xb, wb, kb, 4096, 1024, 4096);

  conv_to_bf16<<<GSML, 256, 0, stream>>>(d_in[4], wb, NSML);  // wv
  // V^T = Wv @ X^T: operand-swapped gemm_bt writes vt [1024][4096]
  gemm_bt<bf16><<<dim3(32, 8), 256, 0, stream>>>(wb, xb, vtb, 1024, 4096, 4096);

  rope_kernel<<<32768, 256, 0, stream>>>(qb, kb, pos);

  poison_bf16<<<GBIG, 256, 0, stream>>>(ab);  // x dead now; make non-write loud

  attn_mfma<<<dim3(32, 32, 2), 256, 0, stream>>>(qb, kb, vtb, ab);

  conv_to_bf16<<<GBIG, 256, 0, stream>>>(d_in[5], wb, NBIG);  // wo
  gemm_bt<float><<<dim3(32, 32), 256, 0, stream>>>(ab, wb, out, 4096, 4096, 4096);
}

// Round 6
// 970.040 us; speedup vs baseline: 13.7555x; 1.3188x over previous
//
#include <hip/hip_runtime.h>
#include <hip/hip_bf16.h>

// LlamaSdpaAttention: B=2, S=2048, HIDDEN=4096, NH=32, NKV=8, D=128, theta=5e5
// Round 11 (from passing round-10, 1279 us). Attn rework, GEMMs unchanged:
//  (1) q-tile PAIRING: block x handles q-tiles {x, 31-x} -> exactly 33
//      tile-units per block (was 1..32, 16x imbalance, 6% occupancy).
//  (2) 2-phase pipeline (T3 minimum recipe): double-buffered LDS, stage(t+1)
//      issued BEFORE compute(t), one __syncthreads per tile (drains vmcnt).
//  (3) K/Vt staged via global_load_lds width=16 into LINEAR LDS with
//      XOR-swizzled SOURCE granules (rule #21 pattern: linear dest +
//      inverse-swz source + swz on read). Frag reads go 8 addr/bank -> 2
//      (free tier). Round-5 proved conflicts (2.163e7, bit-identical across
//      rounds 9/10) are K-path, not V-path.
// conv(fp32->bf16) -> gemm(qkv) -> rope -> flash attn (MFMA) -> gemm(out, fp32).

typedef __attribute__((ext_vector_type(8))) short bf16x8;   // 8 bf16 = 4 VGPRs
typedef __attribute__((ext_vector_type(4))) float floatx4;  // MFMA C/D frag
using bf16 = __hip_bfloat16;

#define LOG2E 1.44269504088896340736f

__device__ __forceinline__ void store_out(bf16* p, float v) { *p = __float2bfloat16(v); }
__device__ __forceinline__ void store_out(float* p, float v) { *p = v; }

// async global->LDS, 16B per lane. LDS dest is wave-uniform base; HW writes
// base + lane*16. Global src is per-lane (enables source-side swizzle). [m03/m97/m173]
__device__ __forceinline__ void gload_lds16(const bf16* g, bf16* l)
{
  __builtin_amdgcn_global_load_lds(
      (const __attribute__((address_space(1))) void*)g,
      (__attribute__((address_space(3))) void*)l, 16, 0, 0);
}

// pack two floats into one u32 of 2 bf16 (lo = a, hi = b)
__device__ __forceinline__ unsigned pk2(float a, float b)
{
  union { bf16 h; unsigned short s; } A, B;
  A.h = __float2bfloat16(a);
  B.h = __float2bfloat16(b);
  return (unsigned)A.s | ((unsigned)B.s << 16);
}

// ---------------------------------------------------------------------------
// Convert unknown-dtype (fp32 or bf16) array to bf16.
// ---------------------------------------------------------------------------
__global__ __launch_bounds__(256) void conv_to_bf16(const void* __restrict__ src,
                                                    bf16* __restrict__ dst,
                                                    size_t n)
{
  const unsigned* u32 = (const unsigned*)src;
  int score = 0;
#pragma unroll
  for (int i = 0; i < 16; i++) {
    unsigned e = (u32[i] >> 7) & 0xFF;  // low-half bf16 exponent field
    score += (e >= 0x6E && e <= 0x84) ? 1 : 0;
  }
  const bool is_bf16 = score >= 12;
  size_t i = ((size_t)blockIdx.x * 256 + threadIdx.x) * 8;
  if (i >= n) return;
  if (is_bf16) {
    *(bf16x8*)(dst + i) = *(const bf16x8*)((const bf16*)src + i);
  } else {
    const float* f = (const float*)src;
    bf16 tmp[8];
#pragma unroll
    for (int j = 0; j < 8; j++) tmp[j] = __float2bfloat16(f[i + j]);
    *(bf16x8*)(dst + i) = *(bf16x8*)tmp;
  }
}

// ---------------------------------------------------------------------------
// Poison: fill a bf16 buffer with 0x7070 (~4.6e33) so a silent attn
// non-write explodes the final GEMM.
// ---------------------------------------------------------------------------
__global__ __launch_bounds__(256) void poison_bf16(bf16* __restrict__ dst)
{
  size_t i = ((size_t)blockIdx.x * 256 + threadIdx.x) * 8;
  const short p = 0x7070;
  bf16x8 v = {p, p, p, p, p, p, p, p};
  *(bf16x8*)(dst + i) = v;
}

// ---------------------------------------------------------------------------
// GEMM: C[M,N] = A[M,K] @ B[N,K]^T, bf16 in, fp32 accumulate, OT out.
// 128x128 tile, BK=64, 256 threads (4 waves, each 64x64), 16x16x32 bf16 MFMA.
// Staging: global_load_lds dwordx4 (m97 recipe).
// ---------------------------------------------------------------------------
template <typename OT>
__global__ __launch_bounds__(256) void gemm_bt(const bf16* __restrict__ A,
                                               const bf16* __restrict__ B,
                                               OT* __restrict__ C,
                                               int M, int N, int K)
{
  __shared__ alignas(16) bf16 As[128 * 64];
  __shared__ alignas(16) bf16 Bs[128 * 64];
  const int tid  = threadIdx.x;
  const int wave = tid >> 6, lane = tid & 63;
  const int quad = lane >> 4, m16 = lane & 15;
  const int m0 = blockIdx.y * 128, n0 = blockIdx.x * 128;
  const int wr = (wave >> 1) * 64, wc = (wave & 1) * 64;

  floatx4 acc[4][4];
#pragma unroll
  for (int i = 0; i < 4; i++)
#pragma unroll
    for (int j = 0; j < 4; j++) acc[i][j] = (floatx4){0.f, 0.f, 0.f, 0.f};

  const int lrow = lane >> 3;       // 0..7  (row within 8-row chunk)
  const int lcol = (lane & 7) * 8;  // 0..56

  for (int kt = 0; kt < K; kt += 64) {
#pragma unroll
    for (int c = 0; c < 4; c++) {
      const int chunk = c * 4 + wave;           // 0..15 (uniform per wave)
      const int row = chunk * 8 + lrow;         // 0..127
      gload_lds16(A + (size_t)(m0 + row) * K + kt + lcol, As + chunk * 512);
      gload_lds16(B + (size_t)(n0 + row) * K + kt + lcol, Bs + chunk * 512);
    }
    __syncthreads();  // drains vmcnt before s_barrier
#pragma unroll
    for (int kk = 0; kk < 2; ++kk) {
      bf16x8 a[4], b[4];
#pragma unroll
      for (int i = 0; i < 4; i++)
        a[i] = *(const bf16x8*)(As + (wr + i * 16 + m16) * 64 + kk * 32 + quad * 8);
#pragma unroll
      for (int j = 0; j < 4; j++)
        b[j] = *(const bf16x8*)(Bs + (wc + j * 16 + m16) * 64 + kk * 32 + quad * 8);
#pragma unroll
      for (int i = 0; i < 4; i++)
#pragma unroll
        for (int j = 0; j < 4; j++)
          acc[i][j] = __builtin_amdgcn_mfma_f32_16x16x32_bf16(a[i], b[j], acc[i][j], 0, 0, 0);
    }
    __syncthreads();
  }

  // C/D layout: col = lane&15, row = quad*4 + reg  [verified m89/m91]
  const int row = m0 + wr + quad * 4;
  const int col = n0 + wc + m16;
#pragma unroll
  for (int i = 0; i < 4; i++)
#pragma unroll
    for (int j = 0; j < 4; j++)
#pragma unroll
      for (int r = 0; r < 4; r++)
        store_out(&C[(size_t)(row + i * 16 + r) * N + col + j * 16], acc[i][j][r]);
}

// ---------------------------------------------------------------------------
// RoPE in place on q [4096 x 4096] and k [4096 x 1024].
// ---------------------------------------------------------------------------
__global__ __launch_bounds__(256) void rope_kernel(bf16* __restrict__ q,
                                                   bf16* __restrict__ k,
                                                   const int* __restrict__ pos)
{
  int idx = blockIdx.x * 256 + threadIdx.x;  // 4096 * 2048 threads
  int row = idx >> 11;
  int p   = idx & 2047;
  int h   = p >> 6, j = p & 63;
  const bool p64 = (pos[1] == 0);
  float t = (float)(p64 ? pos[2 * row] : pos[row]);
  // inv_freq = theta^(-j/64) ; log2(500000) = 18.9315685693
  float inv_freq = exp2f(-(float)j * (18.9315685693241741f / 64.0f));
  float fr = t * inv_freq;
  float s, c;
  sincosf(fr, &s, &c);

  size_t base = (size_t)row * 4096 + h * 128 + j;
  float a  = __bfloat162float(q[base]);
  float b2 = __bfloat162float(q[base + 64]);
  q[base]      = __float2bfloat16(a * c - b2 * s);
  q[base + 64] = __float2bfloat16(b2 * c + a * s);
  if (h < 8) {
    size_t kb = (size_t)row * 1024 + h * 128 + j;
    a  = __bfloat162float(k[kb]);
    b2 = __bfloat162float(k[kb + 64]);
    k[kb]      = __float2bfloat16(a * c - b2 * s);
    k[kb + 64] = __float2bfloat16(b2 * c + a * s);
  }
}

// ---------------------------------------------------------------------------
// Flash-style MFMA attention, swapped-operand form, V^T input, 2-phase
// pipelined, paired q-tiles.
//
// Grid: (16, 32, 2). Block = 4 waves; block x handles q-tiles {x, 31-x}
// (33 tile-units each -> perfectly uniform work). Per q-tile: wave w owns
// q rows [q0+16w, q0+16w+16); loop over 64-key tiles, diagonal masked.
//
// QK^T swapped: sacc[j] = mfma(K_frag, Q_frag): sacc[j][r] (lane quad,m16) =
// S[q=m16][key=j*16+quad*4+r]. Softmax per-lane scalar (key-reduce =
// in-lane + shfl_xor 16,32). P->PV-A-operand redistribution via register
// shuffles (verified round 9). No LDS P.
//
// LDS (64 KB, double-buffered, LINEAR + source-XOR-swizzle):
//   Kbuf[2][64][128]  granule(16B) (r,g) holds global K granule (r, g^(r&7))
//   Vbuf[2][128][64]  granule (d,g) holds global Vt granule (d, g^(d&7))
// Staged with gload_lds (HW-linear writes, conflict-free). Frag reads apply
// the same XOR -> 2 addresses/bank (free) instead of 8.
// ---------------------------------------------------------------------------
__global__ __launch_bounds__(256) void attn_mfma(const bf16* __restrict__ q,
                                                 const bf16* __restrict__ k,
                                                 const bf16* __restrict__ vt,
                                                 bf16* __restrict__ o)
{
  __shared__ alignas(16) bf16 Kbuf[2][64 * 128];   // 2 x 16 KB
  __shared__ alignas(16) bf16 Vbuf[2][128 * 64];   // 2 x 16 KB

  const int tid = threadIdx.x, w = tid >> 6, lane = tid & 63;
  const int quad = lane >> 4, m16 = lane & 15;
  const int m7 = m16 & 7;
  const int h = blockIdx.y, b = blockIdx.z, g = h >> 2;
  const float sl2 = 0.08838834764831843f * LOG2E;  // scale folded into log2 dom

  // staging lane geometry (uniform roles across tiles)
  const int kr_off = lane >> 4;            // K: row within 4-row chunk
  const int kg     = lane & 15;            // K: lds granule
  const int vd_off = lane >> 3;            // Vt: row within 8-row chunk
  const int vg     = lane & 7;             // Vt: lds granule

#pragma unroll 1
  for (int half = 0; half < 2; half++) {
    const int qi = half ? (31 - blockIdx.x) : blockIdx.x;
    const int q0 = qi * 64;
    const int ntl = qi + 1;

    // Q fragments (B-operand for swapped QK^T)
    bf16x8 qf[4];
    {
      const bf16* qp = q + (size_t)(b * 2048 + q0 + w * 16 + m16) * 4096 + h * 128 + quad * 8;
#pragma unroll
      for (int kk = 0; kk < 4; kk++) qf[kk] = *(const bf16x8*)(qp + kk * 32);
    }

    floatx4 acc_o[8];
#pragma unroll
    for (int dj = 0; dj < 8; dj++) acc_o[dj] = (floatx4){0.f, 0.f, 0.f, 0.f};
    float m_run = -1e30f;
    float l_run = 0.f;

    // ---- stage tile 0 into buf 0 ----
    {
      const size_t kvbase = (size_t)(b * 2048) * 1024 + g * 128;
      const size_t vbase  = (size_t)(g * 128) * 4096 + b * 2048;
#pragma unroll
      for (int c = 0; c < 4; c++) {
        const int chunk = c * 4 + w;
        const int r = chunk * 4 + kr_off;
        gload_lds16(k + kvbase + (size_t)r * 1024 + (kg ^ (r & 7)) * 8,
                    &Kbuf[0][chunk * 512]);
        const int d = chunk * 8 + vd_off;
        gload_lds16(vt + vbase + (size_t)d * 4096 + (vg ^ (d & 7)) * 8,
                    &Vbuf[0][chunk * 512]);
      }
    }
    __syncthreads();

    int cur = 0;
    for (int t = 0; t < ntl; ++t) {
      // ---- prefetch tile t+1 into the other buffer (async) ----
      if (t + 1 < ntl) {
        const size_t kvbase = (size_t)(b * 2048 + (t + 1) * 64) * 1024 + g * 128;
        const size_t vbase  = (size_t)(g * 128) * 4096 + b * 2048 + (size_t)(t + 1) * 64;
        bf16* Kn = Kbuf[cur ^ 1];
        bf16* Vn = Vbuf[cur ^ 1];
#pragma unroll
        for (int c = 0; c < 4; c++) {
          const int chunk = c * 4 + w;
          const int r = chunk * 4 + kr_off;
          gload_lds16(k + kvbase + (size_t)r * 1024 + (kg ^ (r & 7)) * 8, Kn + chunk * 512);
          const int d = chunk * 8 + vd_off;
          gload_lds16(vt + vbase + (size_t)d * 4096 + (vg ^ (d & 7)) * 8, Vn + chunk * 512);
        }
      }

      const bf16* Kc = Kbuf[cur];
      const bf16* Vc = Vbuf[cur];

      // ---- S^T = K Q^T: sacc[j][r] = S[m16][j*16+quad*4+r] ----
      floatx4 sacc[4];
#pragma unroll
      for (int j = 0; j < 4; j++) sacc[j] = (floatx4){0.f, 0.f, 0.f, 0.f};
#pragma unroll
      for (int kk = 0; kk < 4; kk++) {
        const int sw = ((kk * 4 + quad) ^ m7) * 8;
#pragma unroll
        for (int j = 0; j < 4; j++) {
          bf16x8 kf = *(const bf16x8*)(Kc + (j * 16 + m16) * 128 + sw);
          sacc[j] = __builtin_amdgcn_mfma_f32_16x16x32_bf16(kf, qf[kk], sacc[j], 0, 0, 0);
        }
      }

      // ---- per-lane online softmax for q-row m16 (log2 domain) ----
      const bool diag = (t == ntl - 1);
      float smax = -1e30f;
#pragma unroll
      for (int j = 0; j < 4; j++)
#pragma unroll
        for (int r = 0; r < 4; r++) {
          float s = sacc[j][r] * sl2;
          s = (diag && (j * 16 + quad * 4 + r > w * 16 + m16)) ? -1e30f : s;
          sacc[j][r] = s;
          smax = fmaxf(smax, s);
        }
      smax = fmaxf(smax, __shfl_xor(smax, 16));
      smax = fmaxf(smax, __shfl_xor(smax, 32));
      const float mnew = fmaxf(m_run, smax);
      const float fac = exp2f(m_run - mnew);
      float ps = 0.f;
#pragma unroll
      for (int j = 0; j < 4; j++)
#pragma unroll
        for (int r = 0; r < 4; r++) {
          float p = exp2f(sacc[j][r] - mnew);
          sacc[j][r] = p;
          ps += p;
        }
      ps += __shfl_xor(ps, 16);
      ps += __shfl_xor(ps, 32);
      l_run = l_run * fac + ps;
      m_run = mnew;

      // ---- pack P (bf16 pairs) ----
      unsigned pl[4], ph[4];
#pragma unroll
      for (int j = 0; j < 4; j++) {
        pl[j] = pk2(sacc[j][0], sacc[j][1]);
        ph[j] = pk2(sacc[j][2], sacc[j][3]);
      }

      // ---- rescale acc_o (row = quad*4+r; fac lives at m16 = quad*4+r) ----
      float facr[4];
#pragma unroll
      for (int r = 0; r < 4; r++) facr[r] = __shfl(fac, quad * 20 + r);
#pragma unroll
      for (int dj = 0; dj < 8; dj++)
#pragma unroll
        for (int r = 0; r < 4; r++) acc_o[dj][r] *= facr[r];

      // ---- O += P V ----
      const int sa = (quad & 1) * 32 + m16;
      const int sb = sa + 16;
      const bool hi2 = (quad & 2) != 0;
#pragma unroll
      for (int kk = 0; kk < 2; kk++) {
        union { bf16x8 v8; int u[4]; } PF;
        int a0 = __shfl((int)pl[2 * kk], sa), a1 = __shfl((int)pl[2 * kk + 1], sa);
        int b0 = __shfl((int)ph[2 * kk], sa), b1 = __shfl((int)ph[2 * kk + 1], sa);
        int c0 = __shfl((int)pl[2 * kk], sb), c1 = __shfl((int)pl[2 * kk + 1], sb);
        int d0 = __shfl((int)ph[2 * kk], sb), d1 = __shfl((int)ph[2 * kk + 1], sb);
        PF.u[0] = hi2 ? a1 : a0;  // keys kk*32+quad*8+{0,1}
        PF.u[1] = hi2 ? b1 : b0;  //                  +{2,3}
        PF.u[2] = hi2 ? c1 : c0;  //                  +{4,5}
        PF.u[3] = hi2 ? d1 : d0;  //                  +{6,7}
        const int sw = ((kk * 4 + quad) ^ m7) * 8;
#pragma unroll
        for (int dj = 0; dj < 8; dj++) {
          bf16x8 vf = *(const bf16x8*)(Vc + (dj * 16 + m16) * 64 + sw);
          acc_o[dj] = __builtin_amdgcn_mfma_f32_16x16x32_bf16(PF.v8, vf, acc_o[dj], 0, 0, 0);
        }
      }

      __syncthreads();  // drains prefetch vmcnt; buffer handoff
      cur ^= 1;
    }

    // ---- epilogue: O / l ----
    float linv[4];
#pragma unroll
    for (int r = 0; r < 4; r++) linv[r] = 1.0f / __shfl(l_run, quad * 20 + r);
    const int orow = q0 + w * 16 + quad * 4;
#pragma unroll
    for (int r = 0; r < 4; r++)
#pragma unroll
      for (int dj = 0; dj < 8; dj++)
        o[(size_t)(b * 2048 + orow + r) * 4096 + h * 128 + dj * 16 + m16] =
            __float2bfloat16(acc_o[dj][r] * linv[r]);
    __syncthreads();  // all reads of LDS done before next half re-stages buf0
  }
}

// ---------------------------------------------------------------------------
extern "C" void kernel_launch(void* const* d_in, const int* in_sizes, int n_in,
                              void* d_out, int out_size, void* d_ws, size_t ws_size,
                              hipStream_t stream)
{
  const int* pos = (const int*)d_in[1];
  float* out = (float*)d_out;  // reference output dtype: fp32

  // Workspace layout (112 MB total):
  char* w = (char*)d_ws;
  bf16* xb = (bf16*)w;               // x  converted  [4096][4096]  32 MB
  bf16* ab = xb;                     // attn output aliases xb (x dead by then)
  bf16* wb = (bf16*)(w + (size_t)32 * 1024 * 1024);  // weight staging 32 MB
  bf16* qb = (bf16*)(w + (size_t)64 * 1024 * 1024);  // q  [4096][4096] 32 MB
  bf16* kb = (bf16*)(w + (size_t)96 * 1024 * 1024);  // k  [4096][1024]  8 MB
  bf16* vtb = (bf16*)(w + (size_t)104 * 1024 * 1024);// v^T [1024][4096]  8 MB

  const size_t NBIG = (size_t)4096 * 4096;   // 16.7M elts
  const size_t NSML = (size_t)4096 * 1024;   // 4.2M elts
  const int GBIG = (int)(NBIG / 8 / 256);    // 8192 blocks
  const int GSML = (int)(NSML / 8 / 256);    // 2048 blocks

  conv_to_bf16<<<GBIG, 256, 0, stream>>>(d_in[0], xb, NBIG);  // x

  conv_to_bf16<<<GBIG, 256, 0, stream>>>(d_in[2], wb, NBIG);  // wq
  gemm_bt<bf16><<<dim3(32, 32), 256, 0, stream>>>(xb, wb, qb, 4096, 4096, 4096);

  conv_to_bf16<<<GSML, 256, 0, stream>>>(d_in[3], wb, NSML);  // wk
  gemm_bt<bf16><<<dim3(8, 32), 256, 0, stream>>>(xb, wb, kb, 4096, 1024, 4096);

  conv_to_bf16<<<GSML, 256, 0, stream>>>(d_in[4], wb, NSML);  // wv
  // V^T = Wv @ X^T: operand-swapped gemm_bt writes vt [1024][4096]
  gemm_bt<bf16><<<dim3(32, 8), 256, 0, stream>>>(wb, xb, vtb, 1024, 4096, 4096);

  rope_kernel<<<32768, 256, 0, stream>>>(qb, kb, pos);

  poison_bf16<<<GBIG, 256, 0, stream>>>(ab);  // x dead now; make non-write loud

  attn_mfma<<<dim3(16, 32, 2), 256, 0, stream>>>(qb, kb, vtb, ab);

  conv_to_bf16<<<GBIG, 256, 0, stream>>>(d_in[5], wb, NBIG);  // wo
  gemm_bt<float><<<dim3(32, 32), 256, 0, stream>>>(ab, wb, out, 4096, 4096, 4096);
}